// Round 1
// baseline (1882.869 us; speedup 1.0000x reference)
//
#include <hip/hip_runtime.h>

#define N_NODES 100000
#define E_EDGES 1600000
#define C 128     // IN_C = H1 = H2
#define OUTC 64
#define GROWS 8

// ---------------- degree / norm ----------------
__global__ void k_deg_init(float* __restrict__ deg) {
    int i = blockIdx.x * blockDim.x + threadIdx.x;
    if (i < N_NODES) deg[i] = 1.0f;  // self-loop
}

__global__ void k_deg_count(const int* __restrict__ col, float* __restrict__ deg) {
    int e = blockIdx.x * blockDim.x + threadIdx.x;
    if (e < E_EDGES) atomicAdd(&deg[col[e]], 1.0f);
}

__global__ void k_dinv(float* __restrict__ deg) {
    int i = blockIdx.x * blockDim.x + threadIdx.x;
    if (i < N_NODES) deg[i] = rsqrtf(deg[i]);  // deg >= 1 always
}

// ---------------- GEMM [N,128] @ [128,128] ----------------
// block = 128 threads (one per out col), GROWS rows per block.
__global__ __launch_bounds__(128) void k_gemm128(const float* __restrict__ X,
                                                 const float* __restrict__ W,
                                                 float* __restrict__ H) {
    __shared__ float xs[GROWS][C];
    const int j = threadIdx.x;
    const int r0 = blockIdx.x * GROWS;
    #pragma unroll
    for (int r = 0; r < GROWS; ++r) {
        int row = r0 + r;
        xs[r][j] = (row < N_NODES) ? X[(long long)row * C + j] : 0.f;
    }
    __syncthreads();
    float acc[GROWS];
    #pragma unroll
    for (int r = 0; r < GROWS; ++r) acc[r] = 0.f;
    for (int k = 0; k < C; ++k) {
        float w = W[k * C + j];
        #pragma unroll
        for (int r = 0; r < GROWS; ++r) acc[r] += xs[r][k] * w;
    }
    #pragma unroll
    for (int r = 0; r < GROWS; ++r) {
        int row = r0 + r;
        if (row < N_NODES) H[(long long)row * C + j] = acc[r];
    }
}

// ---------------- aggregation ----------------
// self-loop contribution: A[i] = dinv[i]^2 * H[i]
__global__ void k_self_init(const float* __restrict__ H, const float* __restrict__ dinv,
                            float* __restrict__ A) {
    long long t = (long long)blockIdx.x * blockDim.x + threadIdx.x;
    if (t < (long long)N_NODES * C) {
        int i = (int)(t >> 7);
        float d = dinv[i];
        A[t] = H[t] * d * d;
    }
}

// edge scatter: A[col] += dinv[row]*dinv[col] * H[row]
__global__ void k_scatter(const int* __restrict__ rowi, const int* __restrict__ coli,
                          const float* __restrict__ dinv, const float* __restrict__ H,
                          float* __restrict__ A) {
    long long t = (long long)blockIdx.x * blockDim.x + threadIdx.x;
    if (t < (long long)E_EDGES * C) {
        int e = (int)(t >> 7);
        int f = (int)(t & 127);
        int r = rowi[e], c = coli[e];
        float nrm = dinv[r] * dinv[c];
        atomicAdd(&A[(long long)c * C + f], H[(long long)r * C + f] * nrm);
    }
}

__global__ void k_bias_relu(float* __restrict__ A, const float* __restrict__ b) {
    long long t = (long long)blockIdx.x * blockDim.x + threadIdx.x;
    if (t < (long long)N_NODES * C) {
        int f = (int)(t & 127);
        A[t] = fmaxf(A[t] + b[f], 0.f);
    }
}

// ---------------- epilogue: bias2 + L2 norm + decode + log_softmax ----------------
// one wave (64 threads) per node
__global__ __launch_bounds__(64) void k_final(const float* __restrict__ A2,
                                              const float* __restrict__ b2,
                                              const float* __restrict__ Wd,
                                              const float* __restrict__ bd,
                                              float* __restrict__ out_logp,
                                              float* __restrict__ out_emb) {
    const int i = blockIdx.x;
    const int lane = threadIdx.x;  // 0..63
    __shared__ float fs[C];
    float v0 = A2[(long long)i * C + lane] + b2[lane];
    float v1 = A2[(long long)i * C + 64 + lane] + b2[64 + lane];
    float ss = v0 * v0 + v1 * v1;
    #pragma unroll
    for (int o = 32; o > 0; o >>= 1) ss += __shfl_down(ss, o);
    ss = __shfl(ss, 0);
    float inv = 1.f / (sqrtf(ss) + 1e-12f);
    float f0 = v0 * inv, f1 = v1 * inv;
    out_emb[(long long)i * C + lane] = f0;
    out_emb[(long long)i * C + 64 + lane] = f1;
    fs[lane] = f0;
    fs[64 + lane] = f1;
    __syncthreads();
    float acc = bd[lane];
    #pragma unroll 4
    for (int k = 0; k < C; ++k) acc += fs[k] * Wd[k * OUTC + lane];
    float m = acc;
    #pragma unroll
    for (int o = 32; o > 0; o >>= 1) m = fmaxf(m, __shfl_down(m, o));
    m = __shfl(m, 0);
    float ex = expf(acc - m);
    float s = ex;
    #pragma unroll
    for (int o = 32; o > 0; o >>= 1) s += __shfl_down(s, o);
    s = __shfl(s, 0);
    out_logp[(long long)i * OUTC + lane] = acc - m - logf(s);
}

extern "C" void kernel_launch(void* const* d_in, const int* in_sizes, int n_in,
                              void* d_out, int out_size, void* d_ws, size_t ws_size,
                              hipStream_t stream) {
    const float* x  = (const float*)d_in[0];
    const int*   ei = (const int*)d_in[1];         // int32 on device (JAX x64 off)
    const int* rowi = ei;                          // edge_index[0]
    const int* coli = ei + E_EDGES;                // edge_index[1]
    const float* W1 = (const float*)d_in[2];
    const float* b1 = (const float*)d_in[3];
    const float* W2 = (const float*)d_in[4];
    const float* b2 = (const float*)d_in[5];
    const float* Wd = (const float*)d_in[6];
    const float* bd = (const float*)d_in[7];

    float* out_logp = (float*)d_out;                            // [N,64]
    float* out_emb  = (float*)d_out + (long long)N_NODES * OUTC; // [N,128]

    float* dinv = (float*)d_ws;                  // N
    float* h    = dinv + N_NODES;                // N*C
    float* agg  = h + (long long)N_NODES * C;    // N*C

    const int T = 256;
    // --- norm ---
    k_deg_init<<<(N_NODES + T - 1) / T, T, 0, stream>>>(dinv);
    k_deg_count<<<(E_EDGES + T - 1) / T, T, 0, stream>>>(coli, dinv);
    k_dinv<<<(N_NODES + T - 1) / T, T, 0, stream>>>(dinv);

    const long long nc = (long long)N_NODES * C;
    const long long ec = (long long)E_EDGES * C;
    // --- conv1 ---
    k_gemm128<<<N_NODES / GROWS, 128, 0, stream>>>(x, W1, h);
    k_self_init<<<(int)((nc + T - 1) / T), T, 0, stream>>>(h, dinv, agg);
    k_scatter<<<(int)((ec + T - 1) / T), T, 0, stream>>>(rowi, coli, dinv, h, agg);
    k_bias_relu<<<(int)((nc + T - 1) / T), T, 0, stream>>>(agg, b1);
    // --- conv2 ---
    k_gemm128<<<N_NODES / GROWS, 128, 0, stream>>>(agg, W2, h);
    k_self_init<<<(int)((nc + T - 1) / T), T, 0, stream>>>(h, dinv, agg);
    k_scatter<<<(int)((ec + T - 1) / T), T, 0, stream>>>(rowi, coli, dinv, h, agg);
    // --- epilogue ---
    k_final<<<N_NODES, 64, 0, stream>>>(agg, b2, Wd, bd, out_logp, out_emb);
}

// Round 2
// 792.226 us; speedup vs baseline: 2.3767x; 2.3767x over previous
//
#include <hip/hip_runtime.h>

#define N_NODES 100000
#define E_EDGES 1600000
#define C 128     // IN_C = H1 = H2
#define OUTC 64
#define GROWS 8
#define SCAN_B 256
#define NB_SCAN ((N_NODES + SCAN_B - 1) / SCAN_B)   // 391

// ---------------- degree / CSR build ----------------
__global__ void k_zero_cnt(int* __restrict__ cnt) {
    int i = blockIdx.x * blockDim.x + threadIdx.x;
    if (i < N_NODES) cnt[i] = 0;
}

__global__ void k_count(const int* __restrict__ col, int* __restrict__ cnt) {
    int e = blockIdx.x * blockDim.x + threadIdx.x;
    if (e < E_EDGES) atomicAdd(&cnt[col[e]], 1);
}

__global__ void k_dinv(const int* __restrict__ cnt, float* __restrict__ dinv) {
    int i = blockIdx.x * blockDim.x + threadIdx.x;
    if (i < N_NODES) dinv[i] = rsqrtf((float)(cnt[i] + 1));  // +1 self-loop
}

// exclusive scan, 3-phase
__global__ __launch_bounds__(SCAN_B) void k_scan1(const int* __restrict__ cnt,
                                                  int* __restrict__ part,
                                                  int* __restrict__ bsum) {
    __shared__ int s[SCAN_B];
    int tid = threadIdx.x;
    int i = blockIdx.x * SCAN_B + tid;
    int v = (i < N_NODES) ? cnt[i] : 0;
    s[tid] = v;
    __syncthreads();
    #pragma unroll
    for (int o = 1; o < SCAN_B; o <<= 1) {
        int t = (tid >= o) ? s[tid - o] : 0;
        __syncthreads();
        s[tid] += t;
        __syncthreads();
    }
    if (i < N_NODES) part[i] = s[tid] - v;           // exclusive within block
    if (tid == SCAN_B - 1) bsum[blockIdx.x] = s[tid]; // block total
}

__global__ __launch_bounds__(512) void k_scan2(int* __restrict__ bsum) {
    __shared__ int s[512];
    int tid = threadIdx.x;
    int v = (tid < NB_SCAN) ? bsum[tid] : 0;
    s[tid] = v;
    __syncthreads();
    #pragma unroll
    for (int o = 1; o < 512; o <<= 1) {
        int t = (tid >= o) ? s[tid - o] : 0;
        __syncthreads();
        s[tid] += t;
        __syncthreads();
    }
    if (tid < NB_SCAN) bsum[tid] = s[tid] - v;       // exclusive over blocks
}

__global__ __launch_bounds__(SCAN_B) void k_scan3(const int* __restrict__ part,
                                                  const int* __restrict__ bsum,
                                                  int* __restrict__ off,
                                                  int* __restrict__ cnt) {
    int i = blockIdx.x * SCAN_B + threadIdx.x;
    if (i < N_NODES) {
        off[i] = part[i] + bsum[blockIdx.x];
        cnt[i] = 0;  // becomes fill cursor
    }
    if (i == 0) off[N_NODES] = E_EDGES;
}

// csr entry: .x = src node, .y = bitcast(dinv[src])
__global__ void k_fill(const int* __restrict__ rowi, const int* __restrict__ coli,
                       const float* __restrict__ dinv, const int* __restrict__ off,
                       int* __restrict__ cursor, int2* __restrict__ csr) {
    int e = blockIdx.x * blockDim.x + threadIdx.x;
    if (e < E_EDGES) {
        int r = rowi[e], c = coli[e];
        int pos = off[c] + atomicAdd(&cursor[c], 1);
        csr[pos] = make_int2(r, __float_as_int(dinv[r]));
    }
}

// ---------------- GEMM [N,128] @ [128,128] ----------------
__global__ __launch_bounds__(128) void k_gemm128(const float* __restrict__ X,
                                                 const float* __restrict__ W,
                                                 float* __restrict__ H) {
    __shared__ float xs[GROWS][C];
    const int j = threadIdx.x;
    const int r0 = blockIdx.x * GROWS;
    #pragma unroll
    for (int r = 0; r < GROWS; ++r) {
        int row = r0 + r;
        xs[r][j] = (row < N_NODES) ? X[(long long)row * C + j] : 0.f;
    }
    __syncthreads();
    float acc[GROWS];
    #pragma unroll
    for (int r = 0; r < GROWS; ++r) acc[r] = 0.f;
    for (int k = 0; k < C; ++k) {
        float w = W[k * C + j];
        #pragma unroll
        for (int r = 0; r < GROWS; ++r) acc[r] += xs[r][k] * w;
    }
    #pragma unroll
    for (int r = 0; r < GROWS; ++r) {
        int row = r0 + r;
        if (row < N_NODES) H[(long long)row * C + j] = acc[r];
    }
}

// ---------------- fused aggregation: self + edges + bias (+relu) ----------------
// one wave per node; lane handles feature pair (2*lane, 2*lane+1) as float2
template <bool RELU>
__global__ __launch_bounds__(256) void k_aggregate(const float* __restrict__ H,
                                                   const int2* __restrict__ csr,
                                                   const int* __restrict__ off,
                                                   const float* __restrict__ dinv,
                                                   const float* __restrict__ bias,
                                                   float* __restrict__ A) {
    const int wid = (blockIdx.x * 256 + threadIdx.x) >> 6;   // node
    const int lane = threadIdx.x & 63;
    if (wid >= N_NODES) return;
    const float2* H2 = (const float2*)H;
    const int s = off[wid];
    const int epos = off[wid + 1];
    const float di = dinv[wid];

    float2 hself = H2[wid * 64 + lane];
    float2 acc;
    acc.x = di * hself.x;     // will get one more *di at the end -> di^2 * h_self
    acc.y = di * hself.y;

    int2 ed = (s < epos) ? csr[s] : make_int2(0, 0);
    for (int e = s; e < epos; ++e) {
        int2 cur = ed;
        if (e + 1 < epos) ed = csr[e + 1];           // prefetch next entry
        float w = __int_as_float(cur.y);
        float2 hv = H2[cur.x * 64 + lane];
        acc.x += w * hv.x;
        acc.y += w * hv.y;
    }
    float2 b = ((const float2*)bias)[lane];
    acc.x = acc.x * di + b.x;
    acc.y = acc.y * di + b.y;
    if (RELU) {
        acc.x = fmaxf(acc.x, 0.f);
        acc.y = fmaxf(acc.y, 0.f);
    }
    ((float2*)A)[wid * 64 + lane] = acc;
}

// ---------------- epilogue: L2 norm + decode + log_softmax ----------------
__global__ __launch_bounds__(64) void k_final(const float* __restrict__ A2,
                                              const float* __restrict__ Wd,
                                              const float* __restrict__ bd,
                                              float* __restrict__ out_logp,
                                              float* __restrict__ out_emb) {
    const int i = blockIdx.x;
    const int lane = threadIdx.x;  // 0..63
    __shared__ float fs[C];
    float v0 = A2[(long long)i * C + lane];
    float v1 = A2[(long long)i * C + 64 + lane];
    float ss = v0 * v0 + v1 * v1;
    #pragma unroll
    for (int o = 32; o > 0; o >>= 1) ss += __shfl_down(ss, o);
    ss = __shfl(ss, 0);
    float inv = 1.f / (sqrtf(ss) + 1e-12f);
    float f0 = v0 * inv, f1 = v1 * inv;
    out_emb[(long long)i * C + lane] = f0;
    out_emb[(long long)i * C + 64 + lane] = f1;
    fs[lane] = f0;
    fs[64 + lane] = f1;
    __syncthreads();
    float acc = bd[lane];
    #pragma unroll 4
    for (int k = 0; k < C; ++k) acc += fs[k] * Wd[k * OUTC + lane];
    float m = acc;
    #pragma unroll
    for (int o = 32; o > 0; o >>= 1) m = fmaxf(m, __shfl_down(m, o));
    m = __shfl(m, 0);
    float ex = expf(acc - m);
    float s = ex;
    #pragma unroll
    for (int o = 32; o > 0; o >>= 1) s += __shfl_down(s, o);
    s = __shfl(s, 0);
    out_logp[(long long)i * OUTC + lane] = acc - m - logf(s);
}

extern "C" void kernel_launch(void* const* d_in, const int* in_sizes, int n_in,
                              void* d_out, int out_size, void* d_ws, size_t ws_size,
                              hipStream_t stream) {
    const float* x  = (const float*)d_in[0];
    const int*   ei = (const int*)d_in[1];
    const int* rowi = ei;
    const int* coli = ei + E_EDGES;
    const float* W1 = (const float*)d_in[2];
    const float* b1 = (const float*)d_in[3];
    const float* W2 = (const float*)d_in[4];
    const float* b2 = (const float*)d_in[5];
    const float* Wd = (const float*)d_in[6];
    const float* bd = (const float*)d_in[7];

    float* out_logp = (float*)d_out;                             // [N,64]
    float* out_emb  = (float*)d_out + (long long)N_NODES * OUTC; // [N,128]

    // workspace layout
    char* p = (char*)d_ws;
    float* dinv = (float*)p;            p += sizeof(float) * N_NODES;
    float* h    = (float*)p;            p += sizeof(float) * (size_t)N_NODES * C;
    float* agg  = (float*)p;            p += sizeof(float) * (size_t)N_NODES * C;
    int*   cnt  = (int*)p;              p += sizeof(int) * N_NODES;
    int*   off  = (int*)p;              p += sizeof(int) * (N_NODES + 1);
    int*   part = (int*)p;              p += sizeof(int) * N_NODES;
    int*   bsum = (int*)p;              p += sizeof(int) * 512;
    int2*  csr  = (int2*)p;             p += sizeof(int2) * (size_t)E_EDGES;

    const int T = 256;
    // --- CSR build + norm ---
    k_zero_cnt<<<(N_NODES + T - 1) / T, T, 0, stream>>>(cnt);
    k_count<<<(E_EDGES + T - 1) / T, T, 0, stream>>>(coli, cnt);
    k_dinv<<<(N_NODES + T - 1) / T, T, 0, stream>>>(cnt, dinv);
    k_scan1<<<NB_SCAN, SCAN_B, 0, stream>>>(cnt, part, bsum);
    k_scan2<<<1, 512, 0, stream>>>(bsum);
    k_scan3<<<NB_SCAN, SCAN_B, 0, stream>>>(part, bsum, off, cnt);
    k_fill<<<(E_EDGES + T - 1) / T, T, 0, stream>>>(rowi, coli, dinv, off, cnt, csr);

    // --- conv1: GEMM + aggregate(bias+relu) ---
    k_gemm128<<<N_NODES / GROWS, 128, 0, stream>>>(x, W1, h);
    k_aggregate<true><<<(N_NODES + 3) / 4, 256, 0, stream>>>(h, csr, off, dinv, b1, agg);

    // --- conv2: GEMM + aggregate(bias) ---
    k_gemm128<<<N_NODES / GROWS, 128, 0, stream>>>(agg, W2, h);
    k_aggregate<false><<<(N_NODES + 3) / 4, 256, 0, stream>>>(h, csr, off, dinv, b2, agg);

    // --- epilogue ---
    k_final<<<N_NODES, 64, 0, stream>>>(agg, Wd, bd, out_logp, out_emb);
}

// Round 4
// 692.049 us; speedup vs baseline: 2.7207x; 1.1448x over previous
//
#include <hip/hip_runtime.h>

#define N_NODES 100000
#define E_EDGES 1600000
#define C 128     // IN_C = H1 = H2
#define OUTC 64
#define SCAN_B 256
#define NB_SCAN ((N_NODES + SCAN_B - 1) / SCAN_B)   // 391

// ---------------- degree / CSR build ----------------
__global__ void k_zero_cnt(int* __restrict__ cnt) {
    int i = blockIdx.x * blockDim.x + threadIdx.x;
    if (i < N_NODES) cnt[i] = 0;
}

__global__ void k_count(const int* __restrict__ col, int* __restrict__ cnt) {
    int e = blockIdx.x * blockDim.x + threadIdx.x;
    if (e < E_EDGES) atomicAdd(&cnt[col[e]], 1);
}

__global__ void k_dinv(const int* __restrict__ cnt, float* __restrict__ dinv) {
    int i = blockIdx.x * blockDim.x + threadIdx.x;
    if (i < N_NODES) dinv[i] = rsqrtf((float)(cnt[i] + 1));  // +1 self-loop
}

// exclusive scan, 3-phase
__global__ __launch_bounds__(SCAN_B) void k_scan1(const int* __restrict__ cnt,
                                                  int* __restrict__ part,
                                                  int* __restrict__ bsum) {
    __shared__ int s[SCAN_B];
    int tid = threadIdx.x;
    int i = blockIdx.x * SCAN_B + tid;
    int v = (i < N_NODES) ? cnt[i] : 0;
    s[tid] = v;
    __syncthreads();
    #pragma unroll
    for (int o = 1; o < SCAN_B; o <<= 1) {
        int t = (tid >= o) ? s[tid - o] : 0;
        __syncthreads();
        s[tid] += t;
        __syncthreads();
    }
    if (i < N_NODES) part[i] = s[tid] - v;
    if (tid == SCAN_B - 1) bsum[blockIdx.x] = s[tid];
}

__global__ __launch_bounds__(512) void k_scan2(int* __restrict__ bsum) {
    __shared__ int s[512];
    int tid = threadIdx.x;
    int v = (tid < NB_SCAN) ? bsum[tid] : 0;
    s[tid] = v;
    __syncthreads();
    #pragma unroll
    for (int o = 1; o < 512; o <<= 1) {
        int t = (tid >= o) ? s[tid - o] : 0;
        __syncthreads();
        s[tid] += t;
        __syncthreads();
    }
    if (tid < NB_SCAN) bsum[tid] = s[tid] - v;
}

__global__ __launch_bounds__(SCAN_B) void k_scan3(const int* __restrict__ part,
                                                  const int* __restrict__ bsum,
                                                  int* __restrict__ off,
                                                  int* __restrict__ cnt) {
    int i = blockIdx.x * SCAN_B + threadIdx.x;
    if (i < N_NODES) {
        off[i] = part[i] + bsum[blockIdx.x];
        cnt[i] = 0;  // becomes fill cursor
    }
    if (i == 0) off[N_NODES] = E_EDGES;
}

// csr entry: .x = src node, .y = bitcast(dinv[src])
__global__ void k_fill(const int* __restrict__ rowi, const int* __restrict__ coli,
                       const float* __restrict__ dinv, const int* __restrict__ off,
                       int* __restrict__ cursor, int2* __restrict__ csr) {
    int e = blockIdx.x * blockDim.x + threadIdx.x;
    if (e < E_EDGES) {
        int r = rowi[e], c = coli[e];
        int pos = off[c] + atomicAdd(&cursor[c], 1);
        csr[pos] = make_int2(r, __float_as_int(dinv[r]));
    }
}

// ---------------- register-tiled GEMM [N,128] @ [128,NC] ----------------
// block 256 threads, 64-row tile. NC=128: 8 rows x 4 cols per thread.
// NC=64: 4 rows x 4 cols per thread. X staged in LDS once; no barrier in
// the k-loop so the compiler can software-pipeline the W loads.
template <int NC>
__global__ __launch_bounds__(256) void k_gemm_rt(const float* __restrict__ X,
                                                 const float* __restrict__ W,
                                                 float* __restrict__ H) {
    constexpr int TXM = NC / 4;        // threads spanning cols
    constexpr int TYN = 256 / TXM;     // row groups
    constexpr int RPT = 64 / TYN;      // rows per thread
    __shared__ float xs[64][C];        // 32 KB
    const int t = threadIdx.x;
    const int r0 = blockIdx.x * 64;

    {   // stage 64x128 X tile: 2048 float4, 8 per thread, coalesced
        const float4* X4 = (const float4*)(X + (size_t)r0 * C);
        float4* s4 = (float4*)xs;
        const bool full = (r0 + 64 <= N_NODES);
        #pragma unroll
        for (int i = 0; i < 8; ++i) {
            int li = t + i * 256;
            if (full || (r0 + (li >> 5) < N_NODES)) s4[li] = X4[li];
            else s4[li] = make_float4(0.f, 0.f, 0.f, 0.f);
        }
    }
    __syncthreads();

    const int tx = t % TXM;
    const int ty = t / TXM;
    float acc[RPT][4];
    #pragma unroll
    for (int r = 0; r < RPT; ++r)
        #pragma unroll
        for (int c = 0; c < 4; ++c) acc[r][c] = 0.f;

    for (int k = 0; k < C; k += 4) {
        float4 w[4];
        #pragma unroll
        for (int kk = 0; kk < 4; ++kk)
            w[kk] = *(const float4*)&W[(k + kk) * NC + 4 * tx];
        float4 xr[RPT];
        #pragma unroll
        for (int r = 0; r < RPT; ++r)
            xr[r] = *(const float4*)&xs[ty * RPT + r][k];
        #pragma unroll
        for (int r = 0; r < RPT; ++r) {
            #pragma unroll
            for (int c = 0; c < 4; ++c) {
                float wc0 = ((const float*)&w[0])[c];
                float wc1 = ((const float*)&w[1])[c];
                float wc2 = ((const float*)&w[2])[c];
                float wc3 = ((const float*)&w[3])[c];
                acc[r][c] += xr[r].x * wc0 + xr[r].y * wc1 + xr[r].z * wc2 + xr[r].w * wc3;
            }
        }
    }

    #pragma unroll
    for (int r = 0; r < RPT; ++r) {
        int row = ty * RPT + r;
        if (r0 + row < N_NODES) {
            float4 v = make_float4(acc[r][0], acc[r][1], acc[r][2], acc[r][3]);
            *(float4*)&H[(size_t)(r0 + row) * NC + 4 * tx] = v;
        }
    }
}

// ---------------- fused aggregation: self + edges + bias (+relu / +invn) ----------------
// one wave per node; lane handles feature pair (2*lane, 2*lane+1)
template <bool RELU>
__global__ __launch_bounds__(256) void k_aggregate(const float* __restrict__ H,
                                                   const int2* __restrict__ csr,
                                                   const int* __restrict__ off,
                                                   const float* __restrict__ dinv,
                                                   const float* __restrict__ bias,
                                                   float* __restrict__ A,
                                                   float* __restrict__ invn) {
    const int wid = (blockIdx.x * 256 + threadIdx.x) >> 6;   // node
    const int lane = threadIdx.x & 63;
    if (wid >= N_NODES) return;
    const float2* H2 = (const float2*)H;
    const int s0 = off[wid];
    const int e1 = off[wid + 1];
    const float di = dinv[wid];

    float2 hself = H2[wid * 64 + lane];
    float2 acc;
    acc.x = di * hself.x;     // one more *di at the end -> di^2 * h_self
    acc.y = di * hself.y;

    int e = s0;
    for (; e + 3 < e1; e += 4) {       // 4 outstanding gathers for MLP
        int2 a0 = csr[e], a1 = csr[e + 1], a2 = csr[e + 2], a3 = csr[e + 3];
        float2 h0 = H2[(size_t)a0.x * 64 + lane];
        float2 h1 = H2[(size_t)a1.x * 64 + lane];
        float2 h2 = H2[(size_t)a2.x * 64 + lane];
        float2 h3 = H2[(size_t)a3.x * 64 + lane];
        float w0 = __int_as_float(a0.y), w1 = __int_as_float(a1.y);
        float w2 = __int_as_float(a2.y), w3 = __int_as_float(a3.y);
        acc.x += w0 * h0.x + w1 * h1.x + w2 * h2.x + w3 * h3.x;
        acc.y += w0 * h0.y + w1 * h1.y + w2 * h2.y + w3 * h3.y;
    }
    for (; e < e1; ++e) {
        int2 a = csr[e];
        float w = __int_as_float(a.y);
        float2 hv = H2[(size_t)a.x * 64 + lane];
        acc.x += w * hv.x;
        acc.y += w * hv.y;
    }
    float2 b = ((const float2*)bias)[lane];
    acc.x = acc.x * di + b.x;
    acc.y = acc.y * di + b.y;
    if (RELU) {
        acc.x = fmaxf(acc.x, 0.f);
        acc.y = fmaxf(acc.y, 0.f);
    } else {
        // conv2 epilogue: also produce 1/(||h||+eps) per node
        float ss = acc.x * acc.x + acc.y * acc.y;
        #pragma unroll
        for (int o = 32; o > 0; o >>= 1) ss += __shfl_down(ss, o);
        if (lane == 0) invn[wid] = 1.f / (sqrtf(ss) + 1e-12f);
    }
    ((float2*)A)[wid * 64 + lane] = acc;
}

// ---------------- final: emb = h*invn, logp = log_softmax(G*invn + bd) ----------------
// one wave per node, memory-bound
__global__ __launch_bounds__(256) void k_final2(const float* __restrict__ Hf,
                                                const float* __restrict__ G,
                                                const float* __restrict__ invn,
                                                const float* __restrict__ bd,
                                                float* __restrict__ out_logp,
                                                float* __restrict__ out_emb) {
    const int wid = (blockIdx.x * 256 + threadIdx.x) >> 6;
    const int lane = threadIdx.x & 63;
    if (wid >= N_NODES) return;
    const float inv = invn[wid];
    float2 h = ((const float2*)Hf)[wid * 64 + lane];
    ((float2*)out_emb)[wid * 64 + lane] = make_float2(h.x * inv, h.y * inv);
    float logit = G[wid * 64 + lane] * inv + bd[lane];
    float m = logit;
    #pragma unroll
    for (int o = 32; o > 0; o >>= 1) m = fmaxf(m, __shfl_down(m, o));
    m = __shfl(m, 0);
    float ex = expf(logit - m);
    float s = ex;
    #pragma unroll
    for (int o = 32; o > 0; o >>= 1) s += __shfl_down(s, o);
    s = __shfl(s, 0);
    out_logp[wid * 64 + lane] = logit - m - logf(s);
}

extern "C" void kernel_launch(void* const* d_in, const int* in_sizes, int n_in,
                              void* d_out, int out_size, void* d_ws, size_t ws_size,
                              hipStream_t stream) {
    const float* x  = (const float*)d_in[0];
    const int*   ei = (const int*)d_in[1];
    const int* rowi = ei;
    const int* coli = ei + E_EDGES;
    const float* W1 = (const float*)d_in[2];
    const float* b1 = (const float*)d_in[3];
    const float* W2 = (const float*)d_in[4];
    const float* b2 = (const float*)d_in[5];
    const float* Wd = (const float*)d_in[6];
    const float* bd = (const float*)d_in[7];

    float* out_logp = (float*)d_out;                             // [N,64]
    float* out_emb  = (float*)d_out + (long long)N_NODES * OUTC; // [N,128]

    // workspace layout (all regions 16B-aligned)
    char* p = (char*)d_ws;
    float* dinv = (float*)p;            p += sizeof(float) * N_NODES;
    float* h    = (float*)p;            p += sizeof(float) * (size_t)N_NODES * C;
    float* agg  = (float*)p;            p += sizeof(float) * (size_t)N_NODES * C;
    int*   cnt  = (int*)p;              p += sizeof(int) * N_NODES;
    int*   off  = (int*)p;              p += sizeof(int) * (N_NODES + 4);
    int*   part = (int*)p;              p += sizeof(int) * N_NODES;
    int*   bsum = (int*)p;              p += sizeof(int) * 512;
    int2*  csr  = (int2*)p;             p += sizeof(int2) * (size_t)E_EDGES;
    float* invn = (float*)part;         // part is dead after k_scan3
    float* G    = h;                    // decode logits reuse h (dead after aggregate2)

    const int T = 256;
    // --- CSR build + norm ---
    k_zero_cnt<<<(N_NODES + T - 1) / T, T, 0, stream>>>(cnt);
    k_count<<<(E_EDGES + T - 1) / T, T, 0, stream>>>(coli, cnt);
    k_dinv<<<(N_NODES + T - 1) / T, T, 0, stream>>>(cnt, dinv);
    k_scan1<<<NB_SCAN, SCAN_B, 0, stream>>>(cnt, part, bsum);
    k_scan2<<<1, 512, 0, stream>>>(bsum);
    k_scan3<<<NB_SCAN, SCAN_B, 0, stream>>>(part, bsum, off, cnt);
    k_fill<<<(E_EDGES + T - 1) / T, T, 0, stream>>>(rowi, coli, dinv, off, cnt, csr);

    const int GB = (N_NODES + 63) / 64;   // 1563
    // --- conv1: GEMM + aggregate(bias+relu) ---
    k_gemm_rt<128><<<GB, 256, 0, stream>>>(x, W1, h);
    k_aggregate<true><<<(N_NODES + 3) / 4, 256, 0, stream>>>(h, csr, off, dinv, b1, agg, nullptr);
    // --- conv2: GEMM + aggregate(bias, +invn) ---
    k_gemm_rt<128><<<GB, 256, 0, stream>>>(agg, W2, h);
    k_aggregate<false><<<(N_NODES + 3) / 4, 256, 0, stream>>>(h, csr, off, dinv, b2, agg, invn);
    // --- decode GEMM (raw h2 @ Wd; invn folded in k_final2) ---
    k_gemm_rt<64><<<GB, 256, 0, stream>>>(agg, Wd, G);
    // --- final ---
    k_final2<<<(N_NODES + 3) / 4, 256, 0, stream>>>(agg, G, invn, bd, out_logp, out_emb);
}

// Round 5
// 682.508 us; speedup vs baseline: 2.7587x; 1.0140x over previous
//
#include <hip/hip_runtime.h>

#define N_NODES 100000
#define E_EDGES 1600000
#define C 128     // IN_C = H1 = H2
#define OUTC 64
#define SCAN_B 256
#define NB_SCAN ((N_NODES + SCAN_B - 1) / SCAN_B)   // 391

// rne float->bf16
__device__ inline unsigned short f2bf(float x) {
    unsigned u = __float_as_uint(x);
    unsigned r = u + 0x7fffu + ((u >> 16) & 1u);
    return (unsigned short)(r >> 16);
}

// ---------------- degree / CSR build ----------------
__global__ void k_count(const int* __restrict__ col, int* __restrict__ cnt) {
    int e = blockIdx.x * blockDim.x + threadIdx.x;
    if (e < E_EDGES) atomicAdd(&cnt[col[e]], 1);
}

// scan phase 1 + dinv
__global__ __launch_bounds__(SCAN_B) void k_scan1(const int* __restrict__ cnt,
                                                  int* __restrict__ part,
                                                  int* __restrict__ bsum,
                                                  float* __restrict__ dinv) {
    __shared__ int s[SCAN_B];
    int tid = threadIdx.x;
    int i = blockIdx.x * SCAN_B + tid;
    int v = (i < N_NODES) ? cnt[i] : 0;
    if (i < N_NODES) dinv[i] = rsqrtf((float)(v + 1));  // +1 self-loop
    s[tid] = v;
    __syncthreads();
    #pragma unroll
    for (int o = 1; o < SCAN_B; o <<= 1) {
        int t = (tid >= o) ? s[tid - o] : 0;
        __syncthreads();
        s[tid] += t;
        __syncthreads();
    }
    if (i < N_NODES) part[i] = s[tid] - v;
    if (tid == SCAN_B - 1) bsum[blockIdx.x] = s[tid];
}

__global__ __launch_bounds__(512) void k_scan2(int* __restrict__ bsum) {
    __shared__ int s[512];
    int tid = threadIdx.x;
    int v = (tid < NB_SCAN) ? bsum[tid] : 0;
    s[tid] = v;
    __syncthreads();
    #pragma unroll
    for (int o = 1; o < 512; o <<= 1) {
        int t = (tid >= o) ? s[tid - o] : 0;
        __syncthreads();
        s[tid] += t;
        __syncthreads();
    }
    if (tid < NB_SCAN) bsum[tid] = s[tid] - v;
}

// off[] + absolute cursor init (cursor aliases cnt)
__global__ __launch_bounds__(SCAN_B) void k_scan3(const int* __restrict__ part,
                                                  const int* __restrict__ bsum,
                                                  int* __restrict__ off,
                                                  int* __restrict__ cursor) {
    int i = blockIdx.x * SCAN_B + threadIdx.x;
    if (i < N_NODES) {
        int o = part[i] + bsum[blockIdx.x];
        off[i] = o;
        cursor[i] = o;
    }
    if (i == 0) off[N_NODES] = E_EDGES;
}

// csr entry: src node only (dinv[src] is pre-folded into Hb rows)
__global__ void k_fill(const int* __restrict__ rowi, const int* __restrict__ coli,
                       int* __restrict__ cursor, int* __restrict__ csr) {
    int e = blockIdx.x * blockDim.x + threadIdx.x;
    if (e < E_EDGES) {
        int pos = atomicAdd(&cursor[coli[e]], 1);
        csr[pos] = rowi[e];
    }
}

// ---------------- encoder GEMM [N,128] @ [128,128] -> bf16, rows scaled by dinv ----------------
// block 256, 64-row tile, 8 rows x 4 cols per thread
__global__ __launch_bounds__(256) void k_gemm_enc(const float* __restrict__ X,
                                                  const float* __restrict__ W,
                                                  const float* __restrict__ dinv,
                                                  unsigned short* __restrict__ Hb) {
    __shared__ float xs[64][C];        // 32 KB
    const int t = threadIdx.x;
    const int r0 = blockIdx.x * 64;

    {   // stage 64x128 X tile
        const float4* X4 = (const float4*)(X + (size_t)r0 * C);
        float4* s4 = (float4*)xs;
        const bool full = (r0 + 64 <= N_NODES);
        #pragma unroll
        for (int i = 0; i < 8; ++i) {
            int li = t + i * 256;
            if (full || (r0 + (li >> 5) < N_NODES)) s4[li] = X4[li];
            else s4[li] = make_float4(0.f, 0.f, 0.f, 0.f);
        }
    }
    __syncthreads();

    const int tx = t % 32;             // col group (4 cols)
    const int ty = t / 32;             // row group (8 rows)
    float acc[8][4];
    #pragma unroll
    for (int r = 0; r < 8; ++r)
        #pragma unroll
        for (int c = 0; c < 4; ++c) acc[r][c] = 0.f;

    for (int k = 0; k < C; k += 4) {
        float4 w[4];
        #pragma unroll
        for (int kk = 0; kk < 4; ++kk)
            w[kk] = *(const float4*)&W[(k + kk) * C + 4 * tx];
        float4 xr[8];
        #pragma unroll
        for (int r = 0; r < 8; ++r)
            xr[r] = *(const float4*)&xs[ty * 8 + r][k];
        #pragma unroll
        for (int r = 0; r < 8; ++r) {
            #pragma unroll
            for (int c = 0; c < 4; ++c) {
                acc[r][c] += xr[r].x * ((const float*)&w[0])[c]
                           + xr[r].y * ((const float*)&w[1])[c]
                           + xr[r].z * ((const float*)&w[2])[c]
                           + xr[r].w * ((const float*)&w[3])[c];
            }
        }
    }

    #pragma unroll
    for (int r = 0; r < 8; ++r) {
        int row = r0 + ty * 8 + r;
        if (row < N_NODES) {
            float s = dinv[row];
            uint2 v;
            v.x = (unsigned)f2bf(acc[r][0] * s) | ((unsigned)f2bf(acc[r][1] * s) << 16);
            v.y = (unsigned)f2bf(acc[r][2] * s) | ((unsigned)f2bf(acc[r][3] * s) << 16);
            *(uint2*)&Hb[(size_t)row * C + 4 * tx] = v;
        }
    }
}

// ---------------- fused aggregation over bf16 scaled rows ----------------
// one wave per node; lane reads dword (2 bf16 features)
template <bool RELU>
__global__ __launch_bounds__(256) void k_aggregate(const unsigned int* __restrict__ Hb,
                                                   const int* __restrict__ csr,
                                                   const int* __restrict__ off,
                                                   const float* __restrict__ dinv,
                                                   const float* __restrict__ bias,
                                                   float* __restrict__ A,
                                                   float* __restrict__ invn) {
    const int wid = (blockIdx.x * 256 + threadIdx.x) >> 6;   // node
    const int lane = threadIdx.x & 63;
    if (wid >= N_NODES) return;
    const int s0 = off[wid];
    const int e1 = off[wid + 1];
    const float di = dinv[wid];

    unsigned g = Hb[(size_t)wid * 64 + lane];   // self row (already di-scaled)
    float2 acc;
    acc.x = __uint_as_float(g << 16);
    acc.y = __uint_as_float(g & 0xffff0000u);

    int e = s0;
    for (; e + 3 < e1; e += 4) {
        int a0 = csr[e], a1 = csr[e + 1], a2 = csr[e + 2], a3 = csr[e + 3];
        unsigned g0 = Hb[(size_t)a0 * 64 + lane];
        unsigned g1 = Hb[(size_t)a1 * 64 + lane];
        unsigned g2 = Hb[(size_t)a2 * 64 + lane];
        unsigned g3 = Hb[(size_t)a3 * 64 + lane];
        acc.x += __uint_as_float(g0 << 16) + __uint_as_float(g1 << 16)
               + __uint_as_float(g2 << 16) + __uint_as_float(g3 << 16);
        acc.y += __uint_as_float(g0 & 0xffff0000u) + __uint_as_float(g1 & 0xffff0000u)
               + __uint_as_float(g2 & 0xffff0000u) + __uint_as_float(g3 & 0xffff0000u);
    }
    for (; e < e1; ++e) {
        unsigned gv = Hb[(size_t)csr[e] * 64 + lane];
        acc.x += __uint_as_float(gv << 16);
        acc.y += __uint_as_float(gv & 0xffff0000u);
    }
    float2 b = ((const float2*)bias)[lane];
    acc.x = acc.x * di + b.x;
    acc.y = acc.y * di + b.y;
    if (RELU) {
        acc.x = fmaxf(acc.x, 0.f);
        acc.y = fmaxf(acc.y, 0.f);
    } else {
        float ss = acc.x * acc.x + acc.y * acc.y;
        #pragma unroll
        for (int o = 32; o > 0; o >>= 1) ss += __shfl_down(ss, o);
        if (lane == 0) invn[wid] = 1.f / (sqrtf(ss) + 1e-12f);
    }
    ((float2*)A)[(size_t)wid * 64 + lane] = acc;
}

// ---------------- fused decode: G = X@Wd, logp = log_softmax(G*invn + bd), emb = X*invn ----------
// block 256, 64-row tile; 4 rows x 4 cols per thread (tx in [0,16))
__global__ __launch_bounds__(256) void k_decode(const float* __restrict__ X,
                                                const float* __restrict__ Wd,
                                                const float* __restrict__ bd,
                                                const float* __restrict__ invn,
                                                float* __restrict__ out_logp,
                                                float* __restrict__ out_emb) {
    __shared__ float xs[64][C];        // 32 KB
    __shared__ float sInv[64];
    const int t = threadIdx.x;
    const int r0 = blockIdx.x * 64;

    {
        const float4* X4 = (const float4*)(X + (size_t)r0 * C);
        float4* s4 = (float4*)xs;
        const bool full = (r0 + 64 <= N_NODES);
        #pragma unroll
        for (int i = 0; i < 8; ++i) {
            int li = t + i * 256;
            if (full || (r0 + (li >> 5) < N_NODES)) s4[li] = X4[li];
            else s4[li] = make_float4(0.f, 0.f, 0.f, 0.f);
        }
        if (t < 64) sInv[t] = (r0 + t < N_NODES) ? invn[r0 + t] : 1.f;
    }
    __syncthreads();

    const int tx = t % 16;             // col group (4 cols of 64)
    const int ty = t / 16;             // row group (4 rows)
    float acc[4][4];
    #pragma unroll
    for (int r = 0; r < 4; ++r)
        #pragma unroll
        for (int c = 0; c < 4; ++c) acc[r][c] = 0.f;

    for (int k = 0; k < C; k += 4) {
        float4 w[4];
        #pragma unroll
        for (int kk = 0; kk < 4; ++kk)
            w[kk] = *(const float4*)&Wd[(k + kk) * OUTC + 4 * tx];
        float4 xr[4];
        #pragma unroll
        for (int r = 0; r < 4; ++r)
            xr[r] = *(const float4*)&xs[ty * 4 + r][k];
        #pragma unroll
        for (int r = 0; r < 4; ++r) {
            #pragma unroll
            for (int c = 0; c < 4; ++c) {
                acc[r][c] += xr[r].x * ((const float*)&w[0])[c]
                           + xr[r].y * ((const float*)&w[1])[c]
                           + xr[r].z * ((const float*)&w[2])[c]
                           + xr[r].w * ((const float*)&w[3])[c];
            }
        }
    }

    float4 bdv = *(const float4*)&bd[4 * tx];
    #pragma unroll
    for (int r = 0; r < 4; ++r) {
        int lrow = ty * 4 + r;
        float inv = sInv[lrow];
        float g0 = acc[r][0] * inv + bdv.x;
        float g1 = acc[r][1] * inv + bdv.y;
        float g2 = acc[r][2] * inv + bdv.z;
        float g3 = acc[r][3] * inv + bdv.w;
        // softmax over 64 cols = 16 lanes x 4 vals (lanes with same ty are contiguous)
        float m = fmaxf(fmaxf(g0, g1), fmaxf(g2, g3));
        #pragma unroll
        for (int o = 1; o < 16; o <<= 1) m = fmaxf(m, __shfl_xor(m, o, 16));
        float s = expf(g0 - m) + expf(g1 - m) + expf(g2 - m) + expf(g3 - m);
        #pragma unroll
        for (int o = 1; o < 16; o <<= 1) s += __shfl_xor(s, o, 16);
        float ls = m + logf(s);
        int row = r0 + lrow;
        if (row < N_NODES) {
            float4 v = make_float4(g0 - ls, g1 - ls, g2 - ls, g3 - ls);
            *(float4*)&out_logp[(size_t)row * OUTC + 4 * tx] = v;
        }
    }

    // emb = xs * invn (xs untouched)
    const bool full = (r0 + 64 <= N_NODES);
    const float4* s4 = (const float4*)xs;
    #pragma unroll
    for (int i = 0; i < 8; ++i) {
        int li = t + i * 256;
        int lrow = li >> 5;
        if (full || (r0 + lrow < N_NODES)) {
            float inv = sInv[lrow];
            float4 v = s4[li];
            v.x *= inv; v.y *= inv; v.z *= inv; v.w *= inv;
            *(float4*)&out_emb[(size_t)r0 * C + 4 * li] = v;
        }
    }
}

extern "C" void kernel_launch(void* const* d_in, const int* in_sizes, int n_in,
                              void* d_out, int out_size, void* d_ws, size_t ws_size,
                              hipStream_t stream) {
    const float* x  = (const float*)d_in[0];
    const int*   ei = (const int*)d_in[1];
    const int* rowi = ei;
    const int* coli = ei + E_EDGES;
    const float* W1 = (const float*)d_in[2];
    const float* b1 = (const float*)d_in[3];
    const float* W2 = (const float*)d_in[4];
    const float* b2 = (const float*)d_in[5];
    const float* Wd = (const float*)d_in[6];
    const float* bd = (const float*)d_in[7];

    float* out_logp = (float*)d_out;                             // [N,64]
    float* out_emb  = (float*)d_out + (long long)N_NODES * OUTC; // [N,128]

    // workspace layout (16B-aligned regions)
    char* p = (char*)d_ws;
    float* dinv = (float*)p;             p += sizeof(float) * N_NODES;
    unsigned short* Hb = (unsigned short*)p;  p += sizeof(short) * (size_t)N_NODES * C;
    float* agg  = (float*)p;             p += sizeof(float) * (size_t)N_NODES * C;
    int*   cnt  = (int*)p;               p += sizeof(int) * N_NODES;   // also cursor
    int*   off  = (int*)p;               p += sizeof(int) * (N_NODES + 4);
    int*   part = (int*)p;               p += sizeof(int) * N_NODES;
    int*   bsum = (int*)p;               p += sizeof(int) * 512;
    int*   csr  = (int*)p;               p += sizeof(int) * (size_t)E_EDGES;
    float* invn = (float*)part;          // part dead after k_scan3

    const int T = 256;
    // --- CSR build + norm ---
    hipMemsetAsync(cnt, 0, sizeof(int) * N_NODES, stream);
    k_count<<<(E_EDGES + T - 1) / T, T, 0, stream>>>(coli, cnt);
    k_scan1<<<NB_SCAN, SCAN_B, 0, stream>>>(cnt, part, bsum, dinv);
    k_scan2<<<1, 512, 0, stream>>>(bsum);
    k_scan3<<<NB_SCAN, SCAN_B, 0, stream>>>(part, bsum, off, cnt);
    k_fill<<<(E_EDGES + T - 1) / T, T, 0, stream>>>(rowi, coli, cnt, csr);

    const int GB = (N_NODES + 63) / 64;   // 1563
    // --- conv1 ---
    k_gemm_enc<<<GB, 256, 0, stream>>>(x, W1, dinv, Hb);
    k_aggregate<true><<<(N_NODES + 3) / 4, 256, 0, stream>>>((const unsigned int*)Hb, csr, off, dinv, b1, agg, nullptr);
    // --- conv2 ---
    k_gemm_enc<<<GB, 256, 0, stream>>>(agg, W2, dinv, Hb);
    k_aggregate<false><<<(N_NODES + 3) / 4, 256, 0, stream>>>((const unsigned int*)Hb, csr, off, dinv, b2, agg, invn);
    // --- fused decode ---
    k_decode<<<GB, 256, 0, stream>>>(agg, Wd, bd, invn, out_logp, out_emb);
}

// Round 6
// 562.911 us; speedup vs baseline: 3.3449x; 1.2125x over previous
//
#include <hip/hip_runtime.h>

#define N_NODES 100000
#define E_EDGES 1600000
#define C 128     // IN_C = H1 = H2
#define OUTC 64

// ---- CSR build (two-level counting sort) constants ----
#define NPB 128                                   // nodes per bucket (dest >> 7)
#define NBKT ((N_NODES + NPB - 1) / NPB)          // 782 buckets
#define CB_BLOCKS 64                              // phase A/C blocks
#define CB_THREADS 1024
#define EPB ((E_EDGES + CB_BLOCKS - 1) / CB_BLOCKS)  // 25000 edges/block
#define SCM (NBKT * CB_BLOCKS)                    // 50048 scan elements
#define S1B 1024
#define NSB ((SCM + S1B - 1) / S1B)               // 49

// rne float->bf16
__device__ inline unsigned short f2bf(float x) {
    unsigned u = __float_as_uint(x);
    unsigned r = u + 0x7fffu + ((u >> 16) & 1u);
    return (unsigned short)(r >> 16);
}

// ---------------- Phase A: per-block bucket histogram (LDS, no global atomics) ----------------
__global__ __launch_bounds__(CB_THREADS) void k_hist(const int* __restrict__ coli,
                                                     int* __restrict__ histG) {
    __shared__ int h[NBKT];
    for (int i = threadIdx.x; i < NBKT; i += CB_THREADS) h[i] = 0;
    __syncthreads();
    const int e0 = blockIdx.x * EPB;
    const int e1 = min(e0 + EPB, E_EDGES);
    for (int e = e0 + (int)threadIdx.x; e < e1; e += CB_THREADS)
        atomicAdd(&h[coli[e] >> 7], 1);
    __syncthreads();
    for (int i = threadIdx.x; i < NBKT; i += CB_THREADS)
        histG[i * CB_BLOCKS + blockIdx.x] = h[i];      // bucket-major
}

// ---------------- Phase B: exclusive scan of histG[SCM] -> base[SCM] ----------------
__global__ __launch_bounds__(S1B) void k_scanA(const int* __restrict__ in,
                                               int* __restrict__ base,
                                               int* __restrict__ bsum) {
    __shared__ int s[S1B];
    int tid = threadIdx.x;
    int i = blockIdx.x * S1B + tid;
    int v = (i < SCM) ? in[i] : 0;
    s[tid] = v;
    __syncthreads();
    #pragma unroll
    for (int o = 1; o < S1B; o <<= 1) {
        int t = (tid >= o) ? s[tid - o] : 0;
        __syncthreads();
        s[tid] += t;
        __syncthreads();
    }
    if (i < SCM) base[i] = s[tid] - v;
    if (tid == S1B - 1) bsum[blockIdx.x] = s[tid];
}

__global__ __launch_bounds__(64) void k_scanB(int* __restrict__ bsum) {
    int tid = threadIdx.x;                 // one wave, NSB=49 <= 64
    int v = (tid < NSB) ? bsum[tid] : 0;
    int x = v;
    #pragma unroll
    for (int o = 1; o < 64; o <<= 1) {
        int t = __shfl_up(x, o);
        if (tid >= o) x += t;
    }
    if (tid < NSB) bsum[tid] = x - v;      // exclusive
}

__global__ __launch_bounds__(S1B) void k_scanC(int* __restrict__ base,
                                               const int* __restrict__ bsum) {
    int i = blockIdx.x * S1B + threadIdx.x;
    if (i < SCM) base[i] += bsum[blockIdx.x];
}

// ---------------- Phase C: coarse scatter into bucket-sorted tmp ----------------
// tmp entry: src (17 bits) | dest_low7 << 17
__global__ __launch_bounds__(CB_THREADS) void k_coarse(const int* __restrict__ rowi,
                                                       const int* __restrict__ coli,
                                                       const int* __restrict__ base,
                                                       int* __restrict__ tmp) {
    __shared__ int cur[NBKT];
    for (int i = threadIdx.x; i < NBKT; i += CB_THREADS)
        cur[i] = base[i * CB_BLOCKS + blockIdx.x];
    __syncthreads();
    const int e0 = blockIdx.x * EPB;
    const int e1 = min(e0 + EPB, E_EDGES);
    for (int e = e0 + (int)threadIdx.x; e < e1; e += CB_THREADS) {
        int c = coli[e];
        int pos = atomicAdd(&cur[c >> 7], 1);
        tmp[pos] = rowi[e] | ((c & 127) << 17);
    }
}

// ---------------- Phase D: fine counting-sort within bucket + off[] + dinv[] ----------------
__global__ __launch_bounds__(256) void k_fine(const int* __restrict__ tmp,
                                              const int* __restrict__ base,
                                              int* __restrict__ csr,
                                              int* __restrict__ off,
                                              float* __restrict__ dinv) {
    __shared__ int hist[NPB];
    __shared__ int scn[NPB];
    const int b = blockIdx.x;
    const int tid = threadIdx.x;
    const int bb = base[b * CB_BLOCKS];
    const int be = (b + 1 < NBKT) ? base[(b + 1) * CB_BLOCKS] : E_EDGES;
    if (tid < NPB) hist[tid] = 0;
    __syncthreads();
    for (int i = bb + tid; i < be; i += 256)
        atomicAdd(&hist[(tmp[i] >> 17) & 127], 1);
    __syncthreads();
    if (tid < NPB) scn[tid] = hist[tid];
    __syncthreads();
    #pragma unroll
    for (int o = 1; o < NPB; o <<= 1) {
        int t = (tid < NPB && tid >= o) ? scn[tid - o] : 0;
        __syncthreads();
        if (tid < NPB) scn[tid] += t;
        __syncthreads();
    }
    if (tid < NPB) {
        int node = b * NPB + tid;
        int excl = scn[tid] - hist[tid];       // exclusive within bucket
        if (node < N_NODES) {
            off[node] = bb + excl;
            dinv[node] = rsqrtf((float)(hist[tid] + 1));   // +1 self-loop
        }
        scn[tid] = bb + excl;                  // absolute cursor
    }
    if (b == NBKT - 1 && tid == 0) off[N_NODES] = E_EDGES;
    __syncthreads();
    for (int i = bb + tid; i < be; i += 256) {
        int v = tmp[i];
        int pos = atomicAdd(&scn[(v >> 17) & 127], 1);
        csr[pos] = v & 0x1ffff;
    }
}

// ---------------- encoder GEMM [N,128] @ [128,128] -> bf16, rows scaled by dinv ----------------
__global__ __launch_bounds__(256) void k_gemm_enc(const float* __restrict__ X,
                                                  const float* __restrict__ W,
                                                  const float* __restrict__ dinv,
                                                  unsigned short* __restrict__ Hb) {
    __shared__ float xs[64][C];        // 32 KB
    const int t = threadIdx.x;
    const int r0 = blockIdx.x * 64;

    {   // stage 64x128 X tile
        const float4* X4 = (const float4*)(X + (size_t)r0 * C);
        float4* s4 = (float4*)xs;
        const bool full = (r0 + 64 <= N_NODES);
        #pragma unroll
        for (int i = 0; i < 8; ++i) {
            int li = t + i * 256;
            if (full || (r0 + (li >> 5) < N_NODES)) s4[li] = X4[li];
            else s4[li] = make_float4(0.f, 0.f, 0.f, 0.f);
        }
    }
    __syncthreads();

    const int tx = t % 32;             // col group (4 cols)
    const int ty = t / 32;             // row group (8 rows)
    float acc[8][4];
    #pragma unroll
    for (int r = 0; r < 8; ++r)
        #pragma unroll
        for (int c = 0; c < 4; ++c) acc[r][c] = 0.f;

    for (int k = 0; k < C; k += 4) {
        float4 w[4];
        #pragma unroll
        for (int kk = 0; kk < 4; ++kk)
            w[kk] = *(const float4*)&W[(k + kk) * C + 4 * tx];
        float4 xr[8];
        #pragma unroll
        for (int r = 0; r < 8; ++r)
            xr[r] = *(const float4*)&xs[ty * 8 + r][k];
        #pragma unroll
        for (int r = 0; r < 8; ++r) {
            #pragma unroll
            for (int c = 0; c < 4; ++c) {
                acc[r][c] += xr[r].x * ((const float*)&w[0])[c]
                           + xr[r].y * ((const float*)&w[1])[c]
                           + xr[r].z * ((const float*)&w[2])[c]
                           + xr[r].w * ((const float*)&w[3])[c];
            }
        }
    }

    #pragma unroll
    for (int r = 0; r < 8; ++r) {
        int row = r0 + ty * 8 + r;
        if (row < N_NODES) {
            float s = dinv[row];
            uint2 v;
            v.x = (unsigned)f2bf(acc[r][0] * s) | ((unsigned)f2bf(acc[r][1] * s) << 16);
            v.y = (unsigned)f2bf(acc[r][2] * s) | ((unsigned)f2bf(acc[r][3] * s) << 16);
            *(uint2*)&Hb[(size_t)row * C + 4 * tx] = v;
        }
    }
}

// ---------------- fused aggregation over bf16 scaled rows ----------------
template <bool RELU>
__global__ __launch_bounds__(256) void k_aggregate(const unsigned int* __restrict__ Hb,
                                                   const int* __restrict__ csr,
                                                   const int* __restrict__ off,
                                                   const float* __restrict__ dinv,
                                                   const float* __restrict__ bias,
                                                   float* __restrict__ A,
                                                   float* __restrict__ invn) {
    const int wid = (blockIdx.x * 256 + threadIdx.x) >> 6;   // node
    const int lane = threadIdx.x & 63;
    if (wid >= N_NODES) return;
    const int s0 = off[wid];
    const int e1 = off[wid + 1];
    const float di = dinv[wid];

    unsigned g = Hb[(size_t)wid * 64 + lane];   // self row (already di-scaled)
    float2 acc;
    acc.x = __uint_as_float(g << 16);
    acc.y = __uint_as_float(g & 0xffff0000u);

    int e = s0;
    for (; e + 3 < e1; e += 4) {
        int a0 = csr[e], a1 = csr[e + 1], a2 = csr[e + 2], a3 = csr[e + 3];
        unsigned g0 = Hb[(size_t)a0 * 64 + lane];
        unsigned g1 = Hb[(size_t)a1 * 64 + lane];
        unsigned g2 = Hb[(size_t)a2 * 64 + lane];
        unsigned g3 = Hb[(size_t)a3 * 64 + lane];
        acc.x += __uint_as_float(g0 << 16) + __uint_as_float(g1 << 16)
               + __uint_as_float(g2 << 16) + __uint_as_float(g3 << 16);
        acc.y += __uint_as_float(g0 & 0xffff0000u) + __uint_as_float(g1 & 0xffff0000u)
               + __uint_as_float(g2 & 0xffff0000u) + __uint_as_float(g3 & 0xffff0000u);
    }
    for (; e < e1; ++e) {
        unsigned gv = Hb[(size_t)csr[e] * 64 + lane];
        acc.x += __uint_as_float(gv << 16);
        acc.y += __uint_as_float(gv & 0xffff0000u);
    }
    float2 b = ((const float2*)bias)[lane];
    acc.x = acc.x * di + b.x;
    acc.y = acc.y * di + b.y;
    if (RELU) {
        acc.x = fmaxf(acc.x, 0.f);
        acc.y = fmaxf(acc.y, 0.f);
    } else {
        float ss = acc.x * acc.x + acc.y * acc.y;
        #pragma unroll
        for (int o = 32; o > 0; o >>= 1) ss += __shfl_down(ss, o);
        if (lane == 0) invn[wid] = 1.f / (sqrtf(ss) + 1e-12f);
    }
    ((float2*)A)[(size_t)wid * 64 + lane] = acc;
}

// ---------------- fused decode: G = X@Wd, logp = log_softmax(G*invn + bd), emb = X*invn ----------
__global__ __launch_bounds__(256) void k_decode(const float* __restrict__ X,
                                                const float* __restrict__ Wd,
                                                const float* __restrict__ bd,
                                                const float* __restrict__ invn,
                                                float* __restrict__ out_logp,
                                                float* __restrict__ out_emb) {
    __shared__ float xs[64][C];        // 32 KB
    __shared__ float sInv[64];
    const int t = threadIdx.x;
    const int r0 = blockIdx.x * 64;

    {
        const float4* X4 = (const float4*)(X + (size_t)r0 * C);
        float4* s4 = (float4*)xs;
        const bool full = (r0 + 64 <= N_NODES);
        #pragma unroll
        for (int i = 0; i < 8; ++i) {
            int li = t + i * 256;
            if (full || (r0 + (li >> 5) < N_NODES)) s4[li] = X4[li];
            else s4[li] = make_float4(0.f, 0.f, 0.f, 0.f);
        }
        if (t < 64) sInv[t] = (r0 + t < N_NODES) ? invn[r0 + t] : 1.f;
    }
    __syncthreads();

    const int tx = t % 16;             // col group (4 cols of 64)
    const int ty = t / 16;             // row group (4 rows)
    float acc[4][4];
    #pragma unroll
    for (int r = 0; r < 4; ++r)
        #pragma unroll
        for (int c = 0; c < 4; ++c) acc[r][c] = 0.f;

    for (int k = 0; k < C; k += 4) {
        float4 w[4];
        #pragma unroll
        for (int kk = 0; kk < 4; ++kk)
            w[kk] = *(const float4*)&Wd[(k + kk) * OUTC + 4 * tx];
        float4 xr[4];
        #pragma unroll
        for (int r = 0; r < 4; ++r)
            xr[r] = *(const float4*)&xs[ty * 4 + r][k];
        #pragma unroll
        for (int r = 0; r < 4; ++r) {
            #pragma unroll
            for (int c = 0; c < 4; ++c) {
                acc[r][c] += xr[r].x * ((const float*)&w[0])[c]
                           + xr[r].y * ((const float*)&w[1])[c]
                           + xr[r].z * ((const float*)&w[2])[c]
                           + xr[r].w * ((const float*)&w[3])[c];
            }
        }
    }

    float4 bdv = *(const float4*)&bd[4 * tx];
    #pragma unroll
    for (int r = 0; r < 4; ++r) {
        int lrow = ty * 4 + r;
        float inv = sInv[lrow];
        float g0 = acc[r][0] * inv + bdv.x;
        float g1 = acc[r][1] * inv + bdv.y;
        float g2 = acc[r][2] * inv + bdv.z;
        float g3 = acc[r][3] * inv + bdv.w;
        float m = fmaxf(fmaxf(g0, g1), fmaxf(g2, g3));
        #pragma unroll
        for (int o = 1; o < 16; o <<= 1) m = fmaxf(m, __shfl_xor(m, o, 16));
        float s = expf(g0 - m) + expf(g1 - m) + expf(g2 - m) + expf(g3 - m);
        #pragma unroll
        for (int o = 1; o < 16; o <<= 1) s += __shfl_xor(s, o, 16);
        float ls = m + logf(s);
        int row = r0 + lrow;
        if (row < N_NODES) {
            float4 v = make_float4(g0 - ls, g1 - ls, g2 - ls, g3 - ls);
            *(float4*)&out_logp[(size_t)row * OUTC + 4 * tx] = v;
        }
    }

    const bool full = (r0 + 64 <= N_NODES);
    const float4* s4 = (const float4*)xs;
    #pragma unroll
    for (int i = 0; i < 8; ++i) {
        int li = t + i * 256;
        int lrow = li >> 5;
        if (full || (r0 + lrow < N_NODES)) {
            float inv = sInv[lrow];
            float4 v = s4[li];
            v.x *= inv; v.y *= inv; v.z *= inv; v.w *= inv;
            *(float4*)&out_emb[(size_t)r0 * C + 4 * li] = v;
        }
    }
}

extern "C" void kernel_launch(void* const* d_in, const int* in_sizes, int n_in,
                              void* d_out, int out_size, void* d_ws, size_t ws_size,
                              hipStream_t stream) {
    const float* x  = (const float*)d_in[0];
    const int*   ei = (const int*)d_in[1];
    const int* rowi = ei;
    const int* coli = ei + E_EDGES;
    const float* W1 = (const float*)d_in[2];
    const float* b1 = (const float*)d_in[3];
    const float* W2 = (const float*)d_in[4];
    const float* b2 = (const float*)d_in[5];
    const float* Wd = (const float*)d_in[6];
    const float* bd = (const float*)d_in[7];

    float* out_logp = (float*)d_out;                             // [N,64]
    float* out_emb  = (float*)d_out + (long long)N_NODES * OUTC; // [N,128]

    // workspace layout (16B-aligned regions)
    char* p = (char*)d_ws;
    float* dinv = (float*)p;                  p += sizeof(float) * N_NODES;
    unsigned short* Hb = (unsigned short*)p;  p += sizeof(short) * (size_t)N_NODES * C;
    float* agg   = (float*)p;                 p += sizeof(float) * (size_t)N_NODES * C;
    int*   off   = (int*)p;                   p += sizeof(int) * (N_NODES + 4);
    int*   histG = (int*)p;                   p += sizeof(int) * SCM;
    int*   base  = (int*)p;                   p += sizeof(int) * SCM;
    int*   bsum  = (int*)p;                   p += sizeof(int) * 64;
    int*   tmp   = (int*)p;                   p += sizeof(int) * (size_t)E_EDGES;
    int*   csr   = (int*)p;                   p += sizeof(int) * (size_t)E_EDGES;
    float* invn  = (float*)p;                 p += sizeof(float) * N_NODES;

    // --- CSR build (two-level counting sort), also produces off[] and dinv[] ---
    k_hist<<<CB_BLOCKS, CB_THREADS, 0, stream>>>(coli, histG);
    k_scanA<<<NSB, S1B, 0, stream>>>(histG, base, bsum);
    k_scanB<<<1, 64, 0, stream>>>(bsum);
    k_scanC<<<NSB, S1B, 0, stream>>>(base, bsum);
    k_coarse<<<CB_BLOCKS, CB_THREADS, 0, stream>>>(rowi, coli, base, tmp);
    k_fine<<<NBKT, 256, 0, stream>>>(tmp, base, csr, off, dinv);

    const int GB = (N_NODES + 63) / 64;   // 1563
    // --- conv1 ---
    k_gemm_enc<<<GB, 256, 0, stream>>>(x, W1, dinv, Hb);
    k_aggregate<true><<<(N_NODES + 3) / 4, 256, 0, stream>>>((const unsigned int*)Hb, csr, off, dinv, b1, agg, nullptr);
    // --- conv2 ---
    k_gemm_enc<<<GB, 256, 0, stream>>>(agg, W2, dinv, Hb);
    k_aggregate<false><<<(N_NODES + 3) / 4, 256, 0, stream>>>((const unsigned int*)Hb, csr, off, dinv, b2, agg, invn);
    // --- fused decode ---
    k_decode<<<GB, 256, 0, stream>>>(agg, Wd, bd, invn, out_logp, out_emb);
}

// Round 7
// 436.411 us; speedup vs baseline: 4.3144x; 1.2899x over previous
//
#include <hip/hip_runtime.h>

#define N_NODES 100000
#define E_EDGES 1600000
#define C 128     // IN_C = H1 = H2
#define OUTC 64

// ---- CSR build (two-level counting sort) constants ----
#define NPB 128                                   // nodes per bucket (dest >> 7)
#define NBKT ((N_NODES + NPB - 1) / NPB)          // 782 buckets
#define CB_BLOCKS 64                              // phase A/C blocks
#define CB_THREADS 1024
#define EPB ((E_EDGES + CB_BLOCKS - 1) / CB_BLOCKS)  // 25000 edges/block
#define SCM (NBKT * CB_BLOCKS)                    // 50048 scan elements
#define S1B 1024
#define NSB ((SCM + S1B - 1) / S1B)               // 49

typedef __attribute__((ext_vector_type(8))) short bf16x8;
typedef __attribute__((ext_vector_type(4))) float f32x4;

// rne float->bf16
__device__ inline unsigned short f2bf(float x) {
    unsigned u = __float_as_uint(x);
    unsigned r = u + 0x7fffu + ((u >> 16) & 1u);
    return (unsigned short)(r >> 16);
}

// ---------------- Phase A: per-block bucket histogram ----------------
__global__ __launch_bounds__(CB_THREADS) void k_hist(const int* __restrict__ coli,
                                                     int* __restrict__ histG) {
    __shared__ int h[NBKT];
    for (int i = threadIdx.x; i < NBKT; i += CB_THREADS) h[i] = 0;
    __syncthreads();
    const int e0 = blockIdx.x * EPB;
    const int e1 = min(e0 + EPB, E_EDGES);
    for (int e = e0 + (int)threadIdx.x; e < e1; e += CB_THREADS)
        atomicAdd(&h[coli[e] >> 7], 1);
    __syncthreads();
    for (int i = threadIdx.x; i < NBKT; i += CB_THREADS)
        histG[i * CB_BLOCKS + blockIdx.x] = h[i];      // bucket-major
}

// ---------------- Phase B: exclusive scan of histG[SCM] ----------------
__global__ __launch_bounds__(S1B) void k_scanA(const int* __restrict__ in,
                                               int* __restrict__ base,
                                               int* __restrict__ bsum) {
    __shared__ int s[S1B];
    int tid = threadIdx.x;
    int i = blockIdx.x * S1B + tid;
    int v = (i < SCM) ? in[i] : 0;
    s[tid] = v;
    __syncthreads();
    #pragma unroll
    for (int o = 1; o < S1B; o <<= 1) {
        int t = (tid >= o) ? s[tid - o] : 0;
        __syncthreads();
        s[tid] += t;
        __syncthreads();
    }
    if (i < SCM) base[i] = s[tid] - v;
    if (tid == S1B - 1) bsum[blockIdx.x] = s[tid];
}

__global__ __launch_bounds__(64) void k_scanB(int* __restrict__ bsum) {
    int tid = threadIdx.x;                 // one wave, NSB=49 <= 64
    int v = (tid < NSB) ? bsum[tid] : 0;
    int x = v;
    #pragma unroll
    for (int o = 1; o < 64; o <<= 1) {
        int t = __shfl_up(x, o);
        if (tid >= o) x += t;
    }
    if (tid < NSB) bsum[tid] = x - v;      // exclusive
}

__global__ __launch_bounds__(S1B) void k_scanC(int* __restrict__ base,
                                               const int* __restrict__ bsum) {
    int i = blockIdx.x * S1B + threadIdx.x;
    if (i < SCM) base[i] += bsum[blockIdx.x];
}

// ---------------- Phase C: coarse scatter into bucket-sorted tmp ----------------
__global__ __launch_bounds__(CB_THREADS) void k_coarse(const int* __restrict__ rowi,
                                                       const int* __restrict__ coli,
                                                       const int* __restrict__ base,
                                                       int* __restrict__ tmp) {
    __shared__ int cur[NBKT];
    for (int i = threadIdx.x; i < NBKT; i += CB_THREADS)
        cur[i] = base[i * CB_BLOCKS + blockIdx.x];
    __syncthreads();
    const int e0 = blockIdx.x * EPB;
    const int e1 = min(e0 + EPB, E_EDGES);
    for (int e = e0 + (int)threadIdx.x; e < e1; e += CB_THREADS) {
        int c = coli[e];
        int pos = atomicAdd(&cur[c >> 7], 1);
        tmp[pos] = rowi[e] | ((c & 127) << 17);
    }
}

// ---------------- Phase D: fine counting-sort + off[] + dinv[] ----------------
__global__ __launch_bounds__(256) void k_fine(const int* __restrict__ tmp,
                                              const int* __restrict__ base,
                                              int* __restrict__ csr,
                                              int* __restrict__ off,
                                              float* __restrict__ dinv) {
    __shared__ int hist[NPB];
    __shared__ int scn[NPB];
    const int b = blockIdx.x;
    const int tid = threadIdx.x;
    const int bb = base[b * CB_BLOCKS];
    const int be = (b + 1 < NBKT) ? base[(b + 1) * CB_BLOCKS] : E_EDGES;
    if (tid < NPB) hist[tid] = 0;
    __syncthreads();
    for (int i = bb + tid; i < be; i += 256)
        atomicAdd(&hist[(tmp[i] >> 17) & 127], 1);
    __syncthreads();
    if (tid < NPB) scn[tid] = hist[tid];
    __syncthreads();
    #pragma unroll
    for (int o = 1; o < NPB; o <<= 1) {
        int t = (tid < NPB && tid >= o) ? scn[tid - o] : 0;
        __syncthreads();
        if (tid < NPB) scn[tid] += t;
        __syncthreads();
    }
    if (tid < NPB) {
        int node = b * NPB + tid;
        int excl = scn[tid] - hist[tid];
        if (node < N_NODES) {
            off[node] = bb + excl;
            dinv[node] = rsqrtf((float)(hist[tid] + 1));   // +1 self-loop
        }
        scn[tid] = bb + excl;
    }
    if (b == NBKT - 1 && tid == 0) off[N_NODES] = E_EDGES;
    __syncthreads();
    for (int i = bb + tid; i < be; i += 256) {
        int v = tmp[i];
        int pos = atomicAdd(&scn[(v >> 17) & 127], 1);
        csr[pos] = v & 0x1ffff;
    }
}

// ---------------- W pack: fp32 [128][128] -> bf16 B-fragments ----------------
// frag (t,s,lane): B[k = s*32 + (lane>>4)*8 + j][n = t*16 + (lane&15)], j=0..7
__global__ __launch_bounds__(256) void k_packW(const float* __restrict__ W,
                                               uint4* __restrict__ Wp) {
    int tid = blockIdx.x * 256 + threadIdx.x;   // 0..2047
    int L = tid & 63;
    int ts = tid >> 6;                           // 0..31
    int t = ts >> 2, s = ts & 3;
    int n = t * 16 + (L & 15);
    int k0 = s * 32 + (L >> 4) * 8;
    unsigned e[8];
    #pragma unroll
    for (int j = 0; j < 8; ++j) e[j] = f2bf(W[(k0 + j) * C + n]);
    uint4 v;
    v.x = e[0] | (e[1] << 16);
    v.y = e[2] | (e[3] << 16);
    v.z = e[4] | (e[5] << 16);
    v.w = e[6] | (e[7] << 16);
    Wp[tid] = v;
}

// ---------------- MFMA encoder GEMM [N,128]@[128,128] -> bf16, rows scaled by dinv ----------
// block 256 (4 waves), 64-row tile; wave w handles rows w*16..w*16+15;
// 8 col-tiles x 4 k-steps of 16x16x32 MFMA.
__global__ __launch_bounds__(256) void k_gemm_mfma(const float* __restrict__ X,
                                                   const uint4* __restrict__ Wp,
                                                   const float* __restrict__ dinv,
                                                   unsigned short* __restrict__ Hb) {
    __shared__ float xs[64][C];        // 32 KB, reused as bf16 out-staging
    __shared__ float sd[64];
    const int t = threadIdx.x;
    const int r0 = blockIdx.x * 64;
    const bool full = (r0 + 64 <= N_NODES);

    {   // stage 64x128 X tile (coalesced float4)
        const float4* X4 = (const float4*)(X + (size_t)r0 * C);
        float4* s4 = (float4*)xs;
        #pragma unroll
        for (int i = 0; i < 8; ++i) {
            int li = t + i * 256;
            if (full || (r0 + (li >> 5) < N_NODES)) s4[li] = X4[li];
            else s4[li] = make_float4(0.f, 0.f, 0.f, 0.f);
        }
        if (t < 64) sd[t] = (r0 + t < N_NODES) ? dinv[r0 + t] : 1.f;
    }
    __syncthreads();

    const int w = t >> 6;              // wave 0..3
    const int lane = t & 63;
    const int m = lane & 15;
    const int q = lane >> 4;
    const int arow = w * 16 + m;       // A row this lane reads

    f32x4 acc[8];
    #pragma unroll
    for (int i = 0; i < 8; ++i) acc[i] = (f32x4){0.f, 0.f, 0.f, 0.f};

    const bf16x8* Wp8 = (const bf16x8*)Wp;
    #pragma unroll
    for (int s = 0; s < 4; ++s) {
        const int k0 = s * 32 + q * 8;
        float4 va = *(const float4*)&xs[arow][k0];
        float4 vb = *(const float4*)&xs[arow][k0 + 4];
        bf16x8 a;
        a[0] = (short)f2bf(va.x); a[1] = (short)f2bf(va.y);
        a[2] = (short)f2bf(va.z); a[3] = (short)f2bf(va.w);
        a[4] = (short)f2bf(vb.x); a[5] = (short)f2bf(vb.y);
        a[6] = (short)f2bf(vb.z); a[7] = (short)f2bf(vb.w);
        #pragma unroll
        for (int tt = 0; tt < 8; ++tt) {
            bf16x8 b = Wp8[(tt * 4 + s) * 64 + lane];
            acc[tt] = __builtin_amdgcn_mfma_f32_16x16x32_bf16(a, b, acc[tt], 0, 0, 0);
        }
    }

    __syncthreads();                   // all waves done reading xs
    unsigned short* hb = (unsigned short*)xs;   // 64x128 bf16 staging
    const int lrb = w * 16 + q * 4;
    #pragma unroll
    for (int r = 0; r < 4; ++r) {
        float sc = sd[lrb + r];
        #pragma unroll
        for (int tt = 0; tt < 8; ++tt)
            hb[(lrb + r) * C + tt * 16 + m] = f2bf(acc[tt][r] * sc);
    }
    __syncthreads();

    // coalesced store: 64x128 bf16 = 1024 uint4
    const uint4* src = (const uint4*)hb;
    uint4* dst = (uint4*)(Hb + (size_t)r0 * C);
    #pragma unroll
    for (int i = 0; i < 4; ++i) {
        int li = t + i * 256;
        if (full || (r0 + (li >> 4) < N_NODES)) dst[li] = src[li];
    }
}

// ---------------- fused aggregation over bf16 scaled rows ----------------
template <bool RELU>
__global__ __launch_bounds__(256) void k_aggregate(const unsigned int* __restrict__ Hb,
                                                   const int* __restrict__ csr,
                                                   const int* __restrict__ off,
                                                   const float* __restrict__ dinv,
                                                   const float* __restrict__ bias,
                                                   float* __restrict__ A,
                                                   float* __restrict__ invn) {
    const int wid = (blockIdx.x * 256 + threadIdx.x) >> 6;   // node
    const int lane = threadIdx.x & 63;
    if (wid >= N_NODES) return;
    const int s0 = off[wid];
    const int e1 = off[wid + 1];
    const float di = dinv[wid];

    unsigned g = Hb[(size_t)wid * 64 + lane];   // self row (already di-scaled)
    float2 acc;
    acc.x = __uint_as_float(g << 16);
    acc.y = __uint_as_float(g & 0xffff0000u);

    int e = s0;
    for (; e + 3 < e1; e += 4) {
        int a0 = csr[e], a1 = csr[e + 1], a2 = csr[e + 2], a3 = csr[e + 3];
        unsigned g0 = Hb[(size_t)a0 * 64 + lane];
        unsigned g1 = Hb[(size_t)a1 * 64 + lane];
        unsigned g2 = Hb[(size_t)a2 * 64 + lane];
        unsigned g3 = Hb[(size_t)a3 * 64 + lane];
        acc.x += __uint_as_float(g0 << 16) + __uint_as_float(g1 << 16)
               + __uint_as_float(g2 << 16) + __uint_as_float(g3 << 16);
        acc.y += __uint_as_float(g0 & 0xffff0000u) + __uint_as_float(g1 & 0xffff0000u)
               + __uint_as_float(g2 & 0xffff0000u) + __uint_as_float(g3 & 0xffff0000u);
    }
    for (; e < e1; ++e) {
        unsigned gv = Hb[(size_t)csr[e] * 64 + lane];
        acc.x += __uint_as_float(gv << 16);
        acc.y += __uint_as_float(gv & 0xffff0000u);
    }
    float2 b = ((const float2*)bias)[lane];
    acc.x = acc.x * di + b.x;
    acc.y = acc.y * di + b.y;
    if (RELU) {
        acc.x = fmaxf(acc.x, 0.f);
        acc.y = fmaxf(acc.y, 0.f);
    } else {
        float ss = acc.x * acc.x + acc.y * acc.y;
        #pragma unroll
        for (int o = 32; o > 0; o >>= 1) ss += __shfl_down(ss, o);
        if (lane == 0) invn[wid] = 1.f / (sqrtf(ss) + 1e-12f);
    }
    ((float2*)A)[(size_t)wid * 64 + lane] = acc;
}

// ---------------- fused decode: G = X@Wd, logp = log_softmax(G*invn + bd), emb = X*invn ----------
__global__ __launch_bounds__(256) void k_decode(const float* __restrict__ X,
                                                const float* __restrict__ Wd,
                                                const float* __restrict__ bd,
                                                const float* __restrict__ invn,
                                                float* __restrict__ out_logp,
                                                float* __restrict__ out_emb) {
    __shared__ float xs[64][C];        // 32 KB
    __shared__ float sInv[64];
    const int t = threadIdx.x;
    const int r0 = blockIdx.x * 64;

    {
        const float4* X4 = (const float4*)(X + (size_t)r0 * C);
        float4* s4 = (float4*)xs;
        const bool full = (r0 + 64 <= N_NODES);
        #pragma unroll
        for (int i = 0; i < 8; ++i) {
            int li = t + i * 256;
            if (full || (r0 + (li >> 5) < N_NODES)) s4[li] = X4[li];
            else s4[li] = make_float4(0.f, 0.f, 0.f, 0.f);
        }
        if (t < 64) sInv[t] = (r0 + t < N_NODES) ? invn[r0 + t] : 1.f;
    }
    __syncthreads();

    const int tx = t % 16;             // col group (4 cols of 64)
    const int ty = t / 16;             // row group (4 rows)
    float acc[4][4];
    #pragma unroll
    for (int r = 0; r < 4; ++r)
        #pragma unroll
        for (int c = 0; c < 4; ++c) acc[r][c] = 0.f;

    for (int k = 0; k < C; k += 4) {
        float4 w[4];
        #pragma unroll
        for (int kk = 0; kk < 4; ++kk)
            w[kk] = *(const float4*)&Wd[(k + kk) * OUTC + 4 * tx];
        float4 xr[4];
        #pragma unroll
        for (int r = 0; r < 4; ++r)
            xr[r] = *(const float4*)&xs[ty * 4 + r][k];
        #pragma unroll
        for (int r = 0; r < 4; ++r) {
            #pragma unroll
            for (int c = 0; c < 4; ++c) {
                acc[r][c] += xr[r].x * ((const float*)&w[0])[c]
                           + xr[r].y * ((const float*)&w[1])[c]
                           + xr[r].z * ((const float*)&w[2])[c]
                           + xr[r].w * ((const float*)&w[3])[c];
            }
        }
    }

    float4 bdv = *(const float4*)&bd[4 * tx];
    #pragma unroll
    for (int r = 0; r < 4; ++r) {
        int lrow = ty * 4 + r;
        float inv = sInv[lrow];
        float g0 = acc[r][0] * inv + bdv.x;
        float g1 = acc[r][1] * inv + bdv.y;
        float g2 = acc[r][2] * inv + bdv.z;
        float g3 = acc[r][3] * inv + bdv.w;
        float m = fmaxf(fmaxf(g0, g1), fmaxf(g2, g3));
        #pragma unroll
        for (int o = 1; o < 16; o <<= 1) m = fmaxf(m, __shfl_xor(m, o, 16));
        float s = expf(g0 - m) + expf(g1 - m) + expf(g2 - m) + expf(g3 - m);
        #pragma unroll
        for (int o = 1; o < 16; o <<= 1) s += __shfl_xor(s, o, 16);
        float ls = m + logf(s);
        int row = r0 + lrow;
        if (row < N_NODES) {
            float4 v = make_float4(g0 - ls, g1 - ls, g2 - ls, g3 - ls);
            *(float4*)&out_logp[(size_t)row * OUTC + 4 * tx] = v;
        }
    }

    const bool full = (r0 + 64 <= N_NODES);
    const float4* s4 = (const float4*)xs;
    #pragma unroll
    for (int i = 0; i < 8; ++i) {
        int li = t + i * 256;
        int lrow = li >> 5;
        if (full || (r0 + lrow < N_NODES)) {
            float inv = sInv[lrow];
            float4 v = s4[li];
            v.x *= inv; v.y *= inv; v.z *= inv; v.w *= inv;
            *(float4*)&out_emb[(size_t)r0 * C + 4 * li] = v;
        }
    }
}

extern "C" void kernel_launch(void* const* d_in, const int* in_sizes, int n_in,
                              void* d_out, int out_size, void* d_ws, size_t ws_size,
                              hipStream_t stream) {
    const float* x  = (const float*)d_in[0];
    const int*   ei = (const int*)d_in[1];
    const int* rowi = ei;
    const int* coli = ei + E_EDGES;
    const float* W1 = (const float*)d_in[2];
    const float* b1 = (const float*)d_in[3];
    const float* W2 = (const float*)d_in[4];
    const float* b2 = (const float*)d_in[5];
    const float* Wd = (const float*)d_in[6];
    const float* bd = (const float*)d_in[7];

    float* out_logp = (float*)d_out;                             // [N,64]
    float* out_emb  = (float*)d_out + (long long)N_NODES * OUTC; // [N,128]

    // workspace layout (16B-aligned regions)
    char* p = (char*)d_ws;
    float* dinv = (float*)p;                  p += sizeof(float) * N_NODES;
    unsigned short* Hb = (unsigned short*)p;  p += sizeof(short) * (size_t)N_NODES * C;
    float* agg   = (float*)p;                 p += sizeof(float) * (size_t)N_NODES * C;
    int*   off   = (int*)p;                   p += sizeof(int) * (N_NODES + 4);
    int*   histG = (int*)p;                   p += sizeof(int) * SCM;
    int*   base  = (int*)p;                   p += sizeof(int) * SCM;
    int*   bsum  = (int*)p;                   p += sizeof(int) * 64;
    int*   tmp   = (int*)p;                   p += sizeof(int) * (size_t)E_EDGES;
    int*   csr   = (int*)p;                   p += sizeof(int) * (size_t)E_EDGES;
    float* invn  = (float*)p;                 p += sizeof(float) * N_NODES;
    uint4* Wp1   = (uint4*)p;                 p += sizeof(uint4) * 2048;
    uint4* Wp2   = (uint4*)p;                 p += sizeof(uint4) * 2048;

    // --- CSR build (also produces off[] and dinv[]) + W packs ---
    k_hist<<<CB_BLOCKS, CB_THREADS, 0, stream>>>(coli, histG);
    k_packW<<<8, 256, 0, stream>>>(W1, Wp1);
    k_packW<<<8, 256, 0, stream>>>(W2, Wp2);
    k_scanA<<<NSB, S1B, 0, stream>>>(histG, base, bsum);
    k_scanB<<<1, 64, 0, stream>>>(bsum);
    k_scanC<<<NSB, S1B, 0, stream>>>(base, bsum);
    k_coarse<<<CB_BLOCKS, CB_THREADS, 0, stream>>>(rowi, coli, base, tmp);
    k_fine<<<NBKT, 256, 0, stream>>>(tmp, base, csr, off, dinv);

    const int GB = (N_NODES + 63) / 64;   // 1563
    // --- conv1 ---
    k_gemm_mfma<<<GB, 256, 0, stream>>>(x, Wp1, dinv, Hb);
    k_aggregate<true><<<(N_NODES + 3) / 4, 256, 0, stream>>>((const unsigned int*)Hb, csr, off, dinv, b1, agg, nullptr);
    // --- conv2 ---
    k_gemm_mfma<<<GB, 256, 0, stream>>>(agg, Wp2, dinv, Hb);
    k_aggregate<false><<<(N_NODES + 3) / 4, 256, 0, stream>>>((const unsigned int*)Hb, csr, off, dinv, b2, agg, invn);
    // --- fused decode ---
    k_decode<<<GB, 256, 0, stream>>>(agg, Wd, bd, invn, out_logp, out_emb);
}